// Round 4
// baseline (1301.417 us; speedup 1.0000x reference)
//
#include <hip/hip_runtime.h>
#include <math.h>

#define IMGD 224
#define HW 50176      // 224*224
#define NK 100
#define NB 8
#define OUT_PER_B 76800   // 100*16*16*3 = 300*256
#define NCHUNK 131        // OpenBLAS k-blocking of 50176: 129x384, 320, 320

// ratio = 10.0 / sqrt(224*224/100) in f64, then rounded to f32 when numpy
// multiplies the f32 arange arrays by the weak python scalar.
static __device__ __forceinline__ float ratio_f32() {
  return (float)(10.0 / sqrt(224.0 * 224.0 / 100.0));
}

// ---------- resize matrix A[16][224], jax linear+antialias semantics ----------
__global__ void build_A_kernel(float* __restrict__ A) {
  __shared__ float red[256];
  int p = blockIdx.x;   // 0..15
  int h = threadIdx.x;  // 0..255
  float tri = 0.0f;
  if (h < IMGD) {
    float center = (p + 0.5f) * 14.0f - 0.5f;       // sample_f
    float xd = fabsf(center - (float)h) / 14.0f;    // / kernel_scale
    tri = fmaxf(0.0f, 1.0f - xd);
  }
  red[h] = tri;
  __syncthreads();
  for (int s = 128; s > 0; s >>= 1) {
    if (h < s) red[h] += red[h + s];
    __syncthreads();
  }
  float Z = red[0];
  if (h < IMGD) A[p * IMGD + h] = tri / Z;
}

// ---------- SLIC: grid-init centers (f32, mirroring numpy) ----------
__global__ void init_centers_kernel(const float* __restrict__ x,
                                    float* __restrict__ centers) {
  int b = blockIdx.x, k = threadIdx.x;
  if (k >= NK) return;
  int gy = k / 10, gx = k % 10;
  int cy = (int)((gy + 0.5) * 224.0 / 10.0);  // trunc like .astype(int32)
  int cx = (int)((gx + 0.5) * 224.0 / 10.0);
  int i = cy * IMGD + cx;
  const float ratio = ratio_f32();
  float* c = centers + ((size_t)b * NK + k) * 5;
  c[0] = x[((size_t)b * 3 + 0) * HW + i];
  c[1] = x[((size_t)b * 3 + 1) * HW + i];
  c[2] = x[((size_t)b * 3 + 2) * HW + i];
  c[3] = __fmul_rn((float)cy, ratio);
  c[4] = __fmul_rn((float)cx, ratio);
}

__global__ void zero_f32_kernel(float* __restrict__ p, int n) {
  int i = blockIdx.x * blockDim.x + threadIdx.x;
  if (i < n) p[i] = 0.0f;
}

// ---------- assignment, f32 bit-mirror of numpy expression ----------
__global__ void __launch_bounds__(256) assign_kernel(
    const float* __restrict__ x, const float* __restrict__ centers,
    int* __restrict__ labels) {
  __shared__ float sc[NK * 5];
  __shared__ float sc2[NK];
  int b = blockIdx.y;
  int tid = threadIdx.x;
  int i = blockIdx.x * 256 + tid;  // grid.x = 196 -> exactly 50176

  for (int t = tid; t < NK * 5; t += 256) sc[t] = centers[(size_t)b * NK * 5 + t];
  __syncthreads();
  if (tid < NK) {
    // c2 = np.sum(centers*centers, axis=1): rounded products, sequential adds
    const float* c = sc + tid * 5;
    float s = __fmul_rn(c[0], c[0]);
    s = __fadd_rn(s, __fmul_rn(c[1], c[1]));
    s = __fadd_rn(s, __fmul_rn(c[2], c[2]));
    s = __fadd_rn(s, __fmul_rn(c[3], c[3]));
    s = __fadd_rn(s, __fmul_rn(c[4], c[4]));
    sc2[tid] = s;
  }
  __syncthreads();

  int y = i / IMGD;
  int xw = i - y * IMGD;
  const float ratio = ratio_f32();
  float f0 = x[((size_t)b * 3 + 0) * HW + i];
  float f1 = x[((size_t)b * 3 + 1) * HW + i];
  float f2 = x[((size_t)b * 3 + 2) * HW + i];
  float f3 = __fmul_rn((float)y, ratio);
  float f4 = __fmul_rn((float)xw, ratio);
  // f2row = np.sum(feat*feat, axis=1): sequential, no FMA
  float fsq = __fmul_rn(f0, f0);
  fsq = __fadd_rn(fsq, __fmul_rn(f1, f1));
  fsq = __fadd_rn(fsq, __fmul_rn(f2, f2));
  fsq = __fadd_rn(fsq, __fmul_rn(f3, f3));
  fsq = __fadd_rn(fsq, __fmul_rn(f4, f4));

  float best = 3.4e38f;
  int bk = 0;
  for (int k = 0; k < NK; ++k) {
    const float* c = sc + k * 5;
    // sgemm k=5 micro-kernel: acc=0, sequential FMA (fma(a0,b0,0)=rounded mul)
    float dot = __fmul_rn(f0, c[0]);
    dot = __fmaf_rn(f1, c[1], dot);
    dot = __fmaf_rn(f2, c[2], dot);
    dot = __fmaf_rn(f3, c[3], dot);
    dot = __fmaf_rn(f4, c[4], dot);
    float d = __fsub_rn(__fadd_rn(fsq, sc2[k]), __fmul_rn(2.0f, dot));
    if (d < best) { best = d; bk = k; }   // first-index wins (np.argmin)
  }
  labels[(size_t)b * HW + i] = bk;
}

// ---------- centroid partials: one k-block of the oh.T@feat sgemm ----------
// Chunk c: pixels [start, start+len), ascending order, f32 sequential adds
// (fma(1.0,x,acc)=fadd; fma(0.0,x,acc)=exact no-op in the BLAS kernel).
__global__ void partial_kernel(const float* __restrict__ x,
                               const int* __restrict__ labels,
                               float* __restrict__ partials) {
  int c = blockIdx.x, b = blockIdx.y;
  int k = threadIdx.x;
  if (k >= NK) return;
  int start = (c < 129) ? c * 384 : 49536 + (c - 129) * 320;
  int len   = (c < 129) ? 384 : 320;
  const float ratio = ratio_f32();
  const int* lb = labels + (size_t)b * HW;
  const float* x0 = x + (size_t)b * 3 * HW;
  float s0 = 0.f, s1 = 0.f, s2 = 0.f, s3 = 0.f, s4 = 0.f, s5 = 0.f;
  for (int t = 0; t < len; ++t) {
    int i = start + t;
    if (lb[i] == k) {
      int y = i / IMGD, xw = i - y * IMGD;
      s0 = __fadd_rn(s0, x0[i]);
      s1 = __fadd_rn(s1, x0[HW + i]);
      s2 = __fadd_rn(s2, x0[2 * HW + i]);
      s3 = __fadd_rn(s3, __fmul_rn((float)y, ratio));
      s4 = __fadd_rn(s4, __fmul_rn((float)xw, ratio));
      s5 += 1.0f;  // counts: exact
    }
  }
  float* p = partials + (((size_t)b * NCHUNK + c) * NK + k) * 6;
  p[0] = s0; p[1] = s1; p[2] = s2; p[3] = s3; p[4] = s4; p[5] = s5;
}

// ---------- combine k-blocks in order + centroid update (all f32) ----------
__global__ void combine_update_kernel(float* __restrict__ centers,
                                      const float* __restrict__ partials) {
  int b = blockIdx.x, k = threadIdx.x;
  if (k >= NK) return;
  float s[6];
  const float* p0 = partials + (((size_t)b * NCHUNK + 0) * NK + k) * 6;
  for (int j = 0; j < 6; ++j) s[j] = p0[j];  // C = 0 + chunk0 (exact)
  for (int c = 1; c < NCHUNK; ++c) {
    const float* p = partials + (((size_t)b * NCHUNK + c) * NK + k) * 6;
    for (int j = 0; j < 6; ++j) s[j] = __fadd_rn(s[j], p[j]);
  }
  float cnt = s[5];
  if (cnt > 0.0f) {                 // where(cnt>0, new, centers)
    float m = fmaxf(cnt, 1.0f);     // np.maximum(cnt, 1.0), exact int in f32
    float* cc = centers + ((size_t)b * NK + k) * 5;
    for (int j = 0; j < 5; ++j) cc[j] = __fdiv_rn(s[j], m);
  }
}

// ---------- scatter-embed: sp[k,p,q,c] += A[p,h]A[q,w]*img, fused layout ----------
__global__ void __launch_bounds__(256) embed_kernel(
    const float* __restrict__ x, const int* __restrict__ labels,
    const float* __restrict__ A, float* __restrict__ out) {
  int b = blockIdx.y;
  int tid = threadIdx.x;
  int i = blockIdx.x * 256 + tid;
  int y = i / IMGD;
  int w = i - y * IMGD;
  int k = labels[(size_t)b * HW + i];
  float v0 = x[((size_t)b * 3 + 0) * HW + i];
  float v1 = x[((size_t)b * 3 + 1) * HW + i];
  float v2 = x[((size_t)b * 3 + 2) * HW + i];
  int pa = (2 * y + 15) / 28;   // floor((y+7.5)/14): upper of the 2 taps
  int qa = (2 * w + 15) / 28;
  float* outb = out + (size_t)b * OUT_PER_B;
  for (int dp = 0; dp < 2; ++dp) {
    int p = pa - 1 + dp;
    if (p < 0 || p > 15) continue;
    float ap = A[p * IMGD + y];
    for (int dq = 0; dq < 2; ++dq) {
      int q = qa - 1 + dq;
      if (q < 0 || q > 15) continue;
      float wgt = ap * A[q * IMGD + w];
      int f = k * 768 + p * 48 + q * 3;  // flat [K,P,P,C] index, c=0
      // out[b, f&255, f>>8]  (view(B,300,256) then transpose)
      unsafeAtomicAdd(outb + (f & 255) * 300 + (f >> 8), wgt * v0);
      int fb = f + 1;
      unsafeAtomicAdd(outb + (fb & 255) * 300 + (fb >> 8), wgt * v1);
      int fc = f + 2;
      unsafeAtomicAdd(outb + (fc & 255) * 300 + (fc >> 8), wgt * v2);
    }
  }
}

extern "C" void kernel_launch(void* const* d_in, const int* in_sizes, int n_in,
                              void* d_out, int out_size, void* d_ws, size_t ws_size,
                              hipStream_t stream) {
  const float* x = (const float*)d_in[0];
  float* out = (float*)d_out;
  char* ws = (char*)d_ws;
  // ws layout:
  float* A        = (float*)(ws);              // 14336 B
  float* centers  = (float*)(ws + 16384);      // 16000 B
  int*   labels   = (int*)(ws + 90112);        // 1605632 B
  float* partials = (float*)(ws + 1703936);    // 8*131*100*6*4 = 2515200 B

  build_A_kernel<<<16, 256, 0, stream>>>(A);
  init_centers_kernel<<<NB, 128, 0, stream>>>(x, centers);

  dim3 pgrid(HW / 256, NB);       // 196 x 8, exact cover
  dim3 cgrid(NCHUNK, NB);         // 131 x 8
  for (int it = 0; it < 10; ++it) {
    assign_kernel<<<pgrid, 256, 0, stream>>>(x, centers, labels);
    partial_kernel<<<cgrid, 128, 0, stream>>>(x, labels, partials);
    combine_update_kernel<<<NB, 128, 0, stream>>>(centers, partials);
  }
  assign_kernel<<<pgrid, 256, 0, stream>>>(x, centers, labels);

  zero_f32_kernel<<<(out_size + 1023) / 1024, 1024, 0, stream>>>(out, out_size);
  embed_kernel<<<pgrid, 256, 0, stream>>>(x, labels, A, out);
}

// Round 5
// 1063.680 us; speedup vs baseline: 1.2235x; 1.2235x over previous
//
#include <hip/hip_runtime.h>
#include <math.h>

#define IMGD 224
#define HW 50176      // 224*224
#define NK 100
#define NB 8
#define OUT_PER_B 76800   // 100*16*16*3 = 300*256
#define NCHUNK 131        // OpenBLAS k-blocking of 50176: 129x384, 320, 320

// ratio = 10.0 / sqrt(224*224/100) in f64, rounded to f32 when numpy multiplies
// the f32 arange arrays by the weak python scalar.
static __device__ __forceinline__ float ratio_f32() {
  return (float)(10.0 / sqrt(224.0 * 224.0 / 100.0));
}

// ---------- resize matrix A[16][224], jax linear+antialias semantics ----------
__global__ void build_A_kernel(float* __restrict__ A) {
  __shared__ float red[256];
  int p = blockIdx.x;   // 0..15
  int h = threadIdx.x;  // 0..255
  float tri = 0.0f;
  if (h < IMGD) {
    float center = (p + 0.5f) * 14.0f - 0.5f;       // sample_f
    float xd = fabsf(center - (float)h) / 14.0f;    // / kernel_scale
    tri = fmaxf(0.0f, 1.0f - xd);
  }
  red[h] = tri;
  __syncthreads();
  for (int s = 128; s > 0; s >>= 1) {
    if (h < s) red[h] += red[h + s];
    __syncthreads();
  }
  float Z = red[0];
  if (h < IMGD) A[p * IMGD + h] = tri / Z;
}

// ---------- SLIC: grid-init centers (f32, mirroring numpy) + c2 ----------
__global__ void init_centers_kernel(const float* __restrict__ x,
                                    float* __restrict__ centers,
                                    float* __restrict__ c2g) {
  int b = blockIdx.x, k = threadIdx.x;
  if (k >= NK) return;
  int gy = k / 10, gx = k % 10;
  int cy = (int)((gy + 0.5) * 224.0 / 10.0);  // trunc like .astype(int32)
  int cx = (int)((gx + 0.5) * 224.0 / 10.0);
  int i = cy * IMGD + cx;
  const float ratio = ratio_f32();
  float c0 = x[((size_t)b * 3 + 0) * HW + i];
  float c1 = x[((size_t)b * 3 + 1) * HW + i];
  float c2 = x[((size_t)b * 3 + 2) * HW + i];
  float c3 = __fmul_rn((float)cy, ratio);
  float c4 = __fmul_rn((float)cx, ratio);
  float* c = centers + ((size_t)b * NK + k) * 5;
  c[0] = c0; c[1] = c1; c[2] = c2; c[3] = c3; c[4] = c4;
  // c2 = np.sum(centers*centers, axis=1): rounded products, sequential adds
  float s = __fmul_rn(c0, c0);
  s = __fadd_rn(s, __fmul_rn(c1, c1));
  s = __fadd_rn(s, __fmul_rn(c2, c2));
  s = __fadd_rn(s, __fmul_rn(c3, c3));
  s = __fadd_rn(s, __fmul_rn(c4, c4));
  c2g[(size_t)b * NK + k] = s;
}

// ---------- assignment, f32 bit-mirror; centers via uniform (SGPR) loads ----------
__global__ void __launch_bounds__(256) assign_kernel(
    const float* __restrict__ x, const float* __restrict__ centers,
    const float* __restrict__ c2g, int* __restrict__ labels) {
  int b = blockIdx.y;
  int tid = threadIdx.x;
  int i = blockIdx.x * 256 + tid;  // grid.x = 196 -> exactly 50176

  int y = i / IMGD;
  int xw = i - y * IMGD;
  const float ratio = ratio_f32();
  float f0 = x[((size_t)b * 3 + 0) * HW + i];
  float f1 = x[((size_t)b * 3 + 1) * HW + i];
  float f2 = x[((size_t)b * 3 + 2) * HW + i];
  float f3 = __fmul_rn((float)y, ratio);
  float f4 = __fmul_rn((float)xw, ratio);
  // f2row = np.sum(feat*feat, axis=1): sequential, no FMA
  float fsq = __fmul_rn(f0, f0);
  fsq = __fadd_rn(fsq, __fmul_rn(f1, f1));
  fsq = __fadd_rn(fsq, __fmul_rn(f2, f2));
  fsq = __fadd_rn(fsq, __fmul_rn(f3, f3));
  fsq = __fadd_rn(fsq, __fmul_rn(f4, f4));

  const float* cb = centers + (size_t)b * NK * 5;   // block-uniform base
  const float* c2b = c2g + (size_t)b * NK;

  float best = 3.4e38f;
  int bk = 0;
  for (int k = 0; k < NK; ++k) {
    // block-uniform addresses -> s_load + SGPR-operand VALU
    float c0 = cb[k * 5 + 0], c1 = cb[k * 5 + 1], c2 = cb[k * 5 + 2];
    float c3 = cb[k * 5 + 3], c4 = cb[k * 5 + 4];
    // sgemm k=5 micro-kernel: acc=0, sequential FMA (fma(a,b,0)=rounded mul)
    float dot = __fmul_rn(f0, c0);
    dot = __fmaf_rn(f1, c1, dot);
    dot = __fmaf_rn(f2, c2, dot);
    dot = __fmaf_rn(f3, c3, dot);
    dot = __fmaf_rn(f4, c4, dot);
    float d = __fsub_rn(__fadd_rn(fsq, c2b[k]), __fmul_rn(2.0f, dot));
    if (d < best) { best = d; bk = k; }   // first-index wins (np.argmin)
  }
  labels[(size_t)b * HW + i] = bk;
}

// ---------- centroid partials: one k-block of the oh.T@feat sgemm ----------
// Chunk c: pixels [start, start+len), ascending order, f32 sequential adds.
__global__ void partial_kernel(const float* __restrict__ x,
                               const int* __restrict__ labels,
                               float* __restrict__ partials) {
  int c = blockIdx.x, b = blockIdx.y;
  int k = threadIdx.x;
  if (k >= NK) return;
  int start = (c < 129) ? c * 384 : 49536 + (c - 129) * 320;
  int len   = (c < 129) ? 384 : 320;
  const float ratio = ratio_f32();
  const int* lb = labels + (size_t)b * HW;
  const float* x0 = x + (size_t)b * 3 * HW;
  float s0 = 0.f, s1 = 0.f, s2 = 0.f, s3 = 0.f, s4 = 0.f, s5 = 0.f;
  for (int t = 0; t < len; ++t) {
    int i = start + t;
    if (lb[i] == k) {
      int y = i / IMGD, xw = i - y * IMGD;
      s0 = __fadd_rn(s0, x0[i]);
      s1 = __fadd_rn(s1, x0[HW + i]);
      s2 = __fadd_rn(s2, x0[2 * HW + i]);
      s3 = __fadd_rn(s3, __fmul_rn((float)y, ratio));
      s4 = __fadd_rn(s4, __fmul_rn((float)xw, ratio));
      s5 += 1.0f;  // counts: exact
    }
  }
  float* p = partials + (((size_t)b * NCHUNK + c) * NK + k) * 6;
  p[0] = s0; p[1] = s1; p[2] = s2; p[3] = s3; p[4] = s4; p[5] = s5;
}

// ---------- combine k-blocks in order + centroid update + c2 (all f32) ----------
__global__ void combine_update_kernel(float* __restrict__ centers,
                                      const float* __restrict__ partials,
                                      float* __restrict__ c2g) {
  int b = blockIdx.x, k = threadIdx.x;
  if (k >= NK) return;
  float s[6];
  const float* p0 = partials + (((size_t)b * NCHUNK + 0) * NK + k) * 6;
  for (int j = 0; j < 6; ++j) s[j] = p0[j];  // C = 0 + chunk0 (exact)
  for (int c = 1; c < NCHUNK; ++c) {
    const float* p = partials + (((size_t)b * NCHUNK + c) * NK + k) * 6;
    for (int j = 0; j < 6; ++j) s[j] = __fadd_rn(s[j], p[j]);
  }
  float* cc = centers + ((size_t)b * NK + k) * 5;
  float cnt = s[5];
  if (cnt > 0.0f) {                 // where(cnt>0, new, centers)
    float m = fmaxf(cnt, 1.0f);     // np.maximum(cnt, 1.0): exact int in f32
    for (int j = 0; j < 5; ++j) cc[j] = __fdiv_rn(s[j], m);
  }
  // recompute c2 from the (possibly unchanged) stored center, same op order
  float c0 = cc[0], c1 = cc[1], c2 = cc[2], c3 = cc[3], c4 = cc[4];
  float t = __fmul_rn(c0, c0);
  t = __fadd_rn(t, __fmul_rn(c1, c1));
  t = __fadd_rn(t, __fmul_rn(c2, c2));
  t = __fadd_rn(t, __fmul_rn(c3, c3));
  t = __fadd_rn(t, __fmul_rn(c4, c4));
  c2g[(size_t)b * NK + k] = t;
}

// ---------- embed: block = (b,p,q); LDS bins per (k,c); direct stores ----------
__global__ void __launch_bounds__(256) embed_kernel(
    const float* __restrict__ x, const int* __restrict__ labels,
    const float* __restrict__ A, float* __restrict__ out) {
  __shared__ float sk[NK * 3];
  int b = blockIdx.y;
  int p = blockIdx.x >> 4;
  int q = blockIdx.x & 15;
  int tid = threadIdx.x;
  for (int t = tid; t < NK * 3; t += 256) sk[t] = 0.0f;
  __syncthreads();

  // A[p,h] support: h in [14p-7, 14p+20] clipped
  int h0 = max(0, 14 * p - 7), h1 = min(IMGD - 1, 14 * p + 20);
  int w0 = max(0, 14 * q - 7), w1 = min(IMGD - 1, 14 * q + 20);
  int hl = h1 - h0 + 1, wl = w1 - w0 + 1;
  int n = hl * wl;

  const float* xb = x + (size_t)b * 3 * HW;
  const int* lb = labels + (size_t)b * HW;
  const float* Ap = A + p * IMGD;
  const float* Aq = A + q * IMGD;

  for (int idx = tid; idx < n; idx += 256) {
    int dh = idx / wl;
    int hh = h0 + dh;
    int ww = w0 + (idx - dh * wl);
    int i = hh * IMGD + ww;
    float wgt = Ap[hh] * Aq[ww];
    int k = lb[i];
    atomicAdd(&sk[k * 3 + 0], wgt * xb[i]);
    atomicAdd(&sk[k * 3 + 1], wgt * xb[HW + i]);
    atomicAdd(&sk[k * 3 + 2], wgt * xb[2 * HW + i]);
  }
  __syncthreads();

  float* outb = out + (size_t)b * OUT_PER_B;
  int base = p * 48 + q * 3;
  for (int t = tid; t < NK * 3; t += 256) {
    int k = t / 3, c = t - 3 * k;
    int f = k * 768 + base + c;           // flat [K,P,P,C] index
    outb[(f & 255) * 300 + (f >> 8)] = sk[t];  // view(B,300,256) + transpose
  }
}

extern "C" void kernel_launch(void* const* d_in, const int* in_sizes, int n_in,
                              void* d_out, int out_size, void* d_ws, size_t ws_size,
                              hipStream_t stream) {
  const float* x = (const float*)d_in[0];
  float* out = (float*)d_out;
  char* ws = (char*)d_ws;
  // ws layout:
  float* A        = (float*)(ws);              // 14336 B
  float* centers  = (float*)(ws + 16384);      // 16000 B
  float* c2g      = (float*)(ws + 49152);      // 3200 B
  int*   labels   = (int*)(ws + 90112);        // 1605632 B
  float* partials = (float*)(ws + 1703936);    // 8*131*100*6*4 = 2515200 B

  build_A_kernel<<<16, 256, 0, stream>>>(A);
  init_centers_kernel<<<NB, 128, 0, stream>>>(x, centers, c2g);

  dim3 pgrid(HW / 256, NB);       // 196 x 8, exact cover
  dim3 cgrid(NCHUNK, NB);         // 131 x 8
  for (int it = 0; it < 10; ++it) {
    assign_kernel<<<pgrid, 256, 0, stream>>>(x, centers, c2g, labels);
    partial_kernel<<<cgrid, 128, 0, stream>>>(x, labels, partials);
    combine_update_kernel<<<NB, 128, 0, stream>>>(centers, partials, c2g);
  }
  assign_kernel<<<pgrid, 256, 0, stream>>>(x, centers, c2g, labels);

  dim3 egrid(256, NB);            // (p*16+q) x b
  embed_kernel<<<egrid, 256, 0, stream>>>(x, labels, A, out);
}

// Round 6
// 793.008 us; speedup vs baseline: 1.6411x; 1.3413x over previous
//
#include <hip/hip_runtime.h>
#include <math.h>

#define IMGD 224
#define HW 50176      // 224*224
#define NK 100
#define NB 8
#define OUT_PER_B 76800   // 100*16*16*3 = 300*256
#define NCHUNK 131        // OpenBLAS k-blocking of 50176: 129x384, 320, 320

// ratio = 10.0 / sqrt(224*224/100) in f64, rounded to f32 when numpy multiplies
// the f32 arange arrays by the weak python scalar.
static __device__ __forceinline__ float ratio_f32() {
  return (float)(10.0 / sqrt(224.0 * 224.0 / 100.0));
}

// ---------- resize matrix A[16][224], jax linear+antialias semantics ----------
__global__ void build_A_kernel(float* __restrict__ A) {
  __shared__ float red[256];
  int p = blockIdx.x;   // 0..15
  int h = threadIdx.x;  // 0..255
  float tri = 0.0f;
  if (h < IMGD) {
    float center = (p + 0.5f) * 14.0f - 0.5f;       // sample_f
    float xd = fabsf(center - (float)h) / 14.0f;    // / kernel_scale
    tri = fmaxf(0.0f, 1.0f - xd);
  }
  red[h] = tri;
  __syncthreads();
  for (int s = 128; s > 0; s >>= 1) {
    if (h < s) red[h] += red[h + s];
    __syncthreads();
  }
  float Z = red[0];
  if (h < IMGD) A[p * IMGD + h] = tri / Z;
}

// ---------- SLIC: grid-init centers (f32, mirroring numpy) + c2 ----------
__global__ void init_centers_kernel(const float* __restrict__ x,
                                    float* __restrict__ centers,
                                    float* __restrict__ c2g) {
  int b = blockIdx.x, k = threadIdx.x;
  if (k >= NK) return;
  int gy = k / 10, gx = k % 10;
  int cy = (int)((gy + 0.5) * 224.0 / 10.0);  // trunc like .astype(int32)
  int cx = (int)((gx + 0.5) * 224.0 / 10.0);
  int i = cy * IMGD + cx;
  const float ratio = ratio_f32();
  float c0 = x[((size_t)b * 3 + 0) * HW + i];
  float c1 = x[((size_t)b * 3 + 1) * HW + i];
  float c2 = x[((size_t)b * 3 + 2) * HW + i];
  float c3 = __fmul_rn((float)cy, ratio);
  float c4 = __fmul_rn((float)cx, ratio);
  float* c = centers + ((size_t)b * NK + k) * 5;
  c[0] = c0; c[1] = c1; c[2] = c2; c[3] = c3; c[4] = c4;
  // c2 = np.sum(centers*centers, axis=1): rounded products, sequential adds
  float s = __fmul_rn(c0, c0);
  s = __fadd_rn(s, __fmul_rn(c1, c1));
  s = __fadd_rn(s, __fmul_rn(c2, c2));
  s = __fadd_rn(s, __fmul_rn(c3, c3));
  s = __fadd_rn(s, __fmul_rn(c4, c4));
  c2g[(size_t)b * NK + k] = s;
}

// ---------- assignment, f32 bit-mirror; centers via uniform (SGPR) loads ----------
__global__ void __launch_bounds__(256) assign_kernel(
    const float* __restrict__ x, const float* __restrict__ centers,
    const float* __restrict__ c2g, int* __restrict__ labels) {
  int b = blockIdx.y;
  int tid = threadIdx.x;
  int i = blockIdx.x * 256 + tid;  // grid.x = 196 -> exactly 50176

  int y = i / IMGD;
  int xw = i - y * IMGD;
  const float ratio = ratio_f32();
  float f0 = x[((size_t)b * 3 + 0) * HW + i];
  float f1 = x[((size_t)b * 3 + 1) * HW + i];
  float f2 = x[((size_t)b * 3 + 2) * HW + i];
  float f3 = __fmul_rn((float)y, ratio);
  float f4 = __fmul_rn((float)xw, ratio);
  // f2row = np.sum(feat*feat, axis=1): sequential, no FMA
  float fsq = __fmul_rn(f0, f0);
  fsq = __fadd_rn(fsq, __fmul_rn(f1, f1));
  fsq = __fadd_rn(fsq, __fmul_rn(f2, f2));
  fsq = __fadd_rn(fsq, __fmul_rn(f3, f3));
  fsq = __fadd_rn(fsq, __fmul_rn(f4, f4));

  const float* cb = centers + (size_t)b * NK * 5;   // block-uniform base
  const float* c2b = c2g + (size_t)b * NK;

  float best = 3.4e38f;
  int bk = 0;
  for (int k = 0; k < NK; ++k) {
    // block-uniform addresses -> s_load + SGPR-operand VALU
    float c0 = cb[k * 5 + 0], c1 = cb[k * 5 + 1], c2 = cb[k * 5 + 2];
    float c3 = cb[k * 5 + 3], c4 = cb[k * 5 + 4];
    // sgemm k=5 micro-kernel: acc=0, sequential FMA (fma(a,b,0)=rounded mul)
    float dot = __fmul_rn(f0, c0);
    dot = __fmaf_rn(f1, c1, dot);
    dot = __fmaf_rn(f2, c2, dot);
    dot = __fmaf_rn(f3, c3, dot);
    dot = __fmaf_rn(f4, c4, dot);
    float d = __fsub_rn(__fadd_rn(fsq, c2b[k]), __fmul_rn(2.0f, dot));
    if (d < best) { best = d; bk = k; }   // first-index wins (np.argmin)
  }
  labels[(size_t)b * HW + i] = bk;
}

// ---------- centroid partials: one k-block of the oh.T@feat sgemm ----------
// Bitmask rewrite: membership search is order-free (parallel, LDS atomicOr);
// the per-(k,chunk) f32 add chain stays strictly ascending-pixel-order, so
// results are bit-identical to the sequential scan.
__global__ void __launch_bounds__(128) partial_kernel(
    const float* __restrict__ x, const int* __restrict__ labels,
    float* __restrict__ partials) {
  __shared__ float4 stage[384];          // {r,g,b,-} per chunk pixel
  __shared__ unsigned int mask[NK * 12]; // 12 groups of 32 pixels
  int c = blockIdx.x, b = blockIdx.y;
  int tid = threadIdx.x;
  int start = (c < 129) ? c * 384 : 49536 + (c - 129) * 320;
  int len   = (c < 129) ? 384 : 320;

  for (int t = tid; t < NK * 12; t += 128) mask[t] = 0u;
  __syncthreads();

  const int* lb = labels + (size_t)b * HW;
  const float* x0 = x + (size_t)b * 3 * HW;
  for (int t = tid; t < len; t += 128) {
    int i = start + t;
    int k = lb[i];
    stage[t] = make_float4(x0[i], x0[HW + i], x0[2 * HW + i], 0.0f);
    atomicOr(&mask[k * 12 + (t >> 5)], 1u << (t & 31));
  }
  __syncthreads();

  int k = tid;
  if (k < NK) {
    const float ratio = ratio_f32();
    float s0 = 0.f, s1 = 0.f, s2 = 0.f, s3 = 0.f, s4 = 0.f, s5 = 0.f;
    for (int g = 0; g < 12; ++g) {
      unsigned int m = mask[k * 12 + g];
      while (m) {
        int j = __ffs(m) - 1;   // ascending pixel order within group
        m &= m - 1;
        int t = (g << 5) + j;
        float4 v = stage[t];
        int i = start + t;
        int y = i / IMGD;
        int xw = i - y * IMGD;
        s0 = __fadd_rn(s0, v.x);
        s1 = __fadd_rn(s1, v.y);
        s2 = __fadd_rn(s2, v.z);
        s3 = __fadd_rn(s3, __fmul_rn((float)y, ratio));
        s4 = __fadd_rn(s4, __fmul_rn((float)xw, ratio));
        s5 += 1.0f;  // counts: exact
      }
    }
    float* p = partials + (((size_t)b * NCHUNK + c) * NK + k) * 6;
    p[0] = s0; p[1] = s1; p[2] = s2; p[3] = s3; p[4] = s4; p[5] = s5;
  }
}

// ---------- combine k-blocks in order + centroid update + c2 (all f32) ----------
__global__ void combine_update_kernel(float* __restrict__ centers,
                                      const float* __restrict__ partials,
                                      float* __restrict__ c2g) {
  int b = blockIdx.x, k = threadIdx.x;
  if (k >= NK) return;
  float s[6];
  const float* p0 = partials + (((size_t)b * NCHUNK + 0) * NK + k) * 6;
  for (int j = 0; j < 6; ++j) s[j] = p0[j];  // C = 0 + chunk0 (exact)
  for (int c = 1; c < NCHUNK; ++c) {
    const float* p = partials + (((size_t)b * NCHUNK + c) * NK + k) * 6;
    for (int j = 0; j < 6; ++j) s[j] = __fadd_rn(s[j], p[j]);
  }
  float* cc = centers + ((size_t)b * NK + k) * 5;
  float cnt = s[5];
  if (cnt > 0.0f) {                 // where(cnt>0, new, centers)
    float m = fmaxf(cnt, 1.0f);     // np.maximum(cnt, 1.0): exact int in f32
    for (int j = 0; j < 5; ++j) cc[j] = __fdiv_rn(s[j], m);
  }
  // recompute c2 from the (possibly unchanged) stored center, same op order
  float c0 = cc[0], c1 = cc[1], c2 = cc[2], c3 = cc[3], c4 = cc[4];
  float t = __fmul_rn(c0, c0);
  t = __fadd_rn(t, __fmul_rn(c1, c1));
  t = __fadd_rn(t, __fmul_rn(c2, c2));
  t = __fadd_rn(t, __fmul_rn(c3, c3));
  t = __fadd_rn(t, __fmul_rn(c4, c4));
  c2g[(size_t)b * NK + k] = t;
}

// ---------- embed: block = (b,p,q); LDS bins per (k,c); direct stores ----------
__global__ void __launch_bounds__(256) embed_kernel(
    const float* __restrict__ x, const int* __restrict__ labels,
    const float* __restrict__ A, float* __restrict__ out) {
  __shared__ float sk[NK * 3];
  int b = blockIdx.y;
  int p = blockIdx.x >> 4;
  int q = blockIdx.x & 15;
  int tid = threadIdx.x;
  for (int t = tid; t < NK * 3; t += 256) sk[t] = 0.0f;
  __syncthreads();

  // A[p,h] support: h in [14p-7, 14p+20] clipped
  int h0 = max(0, 14 * p - 7), h1 = min(IMGD - 1, 14 * p + 20);
  int w0 = max(0, 14 * q - 7), w1 = min(IMGD - 1, 14 * q + 20);
  int hl = h1 - h0 + 1, wl = w1 - w0 + 1;
  int n = hl * wl;

  const float* xb = x + (size_t)b * 3 * HW;
  const int* lb = labels + (size_t)b * HW;
  const float* Ap = A + p * IMGD;
  const float* Aq = A + q * IMGD;

  for (int idx = tid; idx < n; idx += 256) {
    int dh = idx / wl;
    int hh = h0 + dh;
    int ww = w0 + (idx - dh * wl);
    int i = hh * IMGD + ww;
    float wgt = Ap[hh] * Aq[ww];
    int k = lb[i];
    atomicAdd(&sk[k * 3 + 0], wgt * xb[i]);
    atomicAdd(&sk[k * 3 + 1], wgt * xb[HW + i]);
    atomicAdd(&sk[k * 3 + 2], wgt * xb[2 * HW + i]);
  }
  __syncthreads();

  float* outb = out + (size_t)b * OUT_PER_B;
  int base = p * 48 + q * 3;
  for (int t = tid; t < NK * 3; t += 256) {
    int k = t / 3, c = t - 3 * k;
    int f = k * 768 + base + c;           // flat [K,P,P,C] index
    outb[(f & 255) * 300 + (f >> 8)] = sk[t];  // view(B,300,256) + transpose
  }
}

extern "C" void kernel_launch(void* const* d_in, const int* in_sizes, int n_in,
                              void* d_out, int out_size, void* d_ws, size_t ws_size,
                              hipStream_t stream) {
  const float* x = (const float*)d_in[0];
  float* out = (float*)d_out;
  char* ws = (char*)d_ws;
  // ws layout:
  float* A        = (float*)(ws);              // 14336 B
  float* centers  = (float*)(ws + 16384);      // 16000 B
  float* c2g      = (float*)(ws + 49152);      // 3200 B
  int*   labels   = (int*)(ws + 90112);        // 1605632 B
  float* partials = (float*)(ws + 1703936);    // 8*131*100*6*4 = 2515200 B

  build_A_kernel<<<16, 256, 0, stream>>>(A);
  init_centers_kernel<<<NB, 128, 0, stream>>>(x, centers, c2g);

  dim3 pgrid(HW / 256, NB);       // 196 x 8, exact cover
  dim3 cgrid(NCHUNK, NB);         // 131 x 8
  for (int it = 0; it < 10; ++it) {
    assign_kernel<<<pgrid, 256, 0, stream>>>(x, centers, c2g, labels);
    partial_kernel<<<cgrid, 128, 0, stream>>>(x, labels, partials);
    combine_update_kernel<<<NB, 128, 0, stream>>>(centers, partials, c2g);
  }
  assign_kernel<<<pgrid, 256, 0, stream>>>(x, centers, c2g, labels);

  dim3 egrid(256, NB);            // (p*16+q) x b
  embed_kernel<<<egrid, 256, 0, stream>>>(x, labels, A, out);
}

// Round 7
// 736.543 us; speedup vs baseline: 1.7669x; 1.0767x over previous
//
#include <hip/hip_runtime.h>
#include <math.h>

#define IMGD 224
#define HW 50176      // 224*224
#define NK 100
#define NB 8
#define OUT_PER_B 76800   // 100*16*16*3 = 300*256
#define NCHUNK 131        // OpenBLAS k-blocking of 50176: 129x384, 320, 320

// ratio = 10.0 / sqrt(224*224/100) in f64, rounded to f32 when numpy multiplies
// the f32 arange arrays by the weak python scalar.
static __device__ __forceinline__ float ratio_f32() {
  return (float)(10.0 / sqrt(224.0 * 224.0 / 100.0));
}

// ---------- resize matrix A[16][224], jax linear+antialias semantics ----------
__global__ void build_A_kernel(float* __restrict__ A) {
  __shared__ float red[256];
  int p = blockIdx.x;   // 0..15
  int h = threadIdx.x;  // 0..255
  float tri = 0.0f;
  if (h < IMGD) {
    float center = (p + 0.5f) * 14.0f - 0.5f;       // sample_f
    float xd = fabsf(center - (float)h) / 14.0f;    // / kernel_scale
    tri = fmaxf(0.0f, 1.0f - xd);
  }
  red[h] = tri;
  __syncthreads();
  for (int s = 128; s > 0; s >>= 1) {
    if (h < s) red[h] += red[h + s];
    __syncthreads();
  }
  float Z = red[0];
  if (h < IMGD) A[p * IMGD + h] = tri / Z;
}

// ---------- SLIC: grid-init centers (f32, mirroring numpy) + c2 ----------
__global__ void init_centers_kernel(const float* __restrict__ x,
                                    float* __restrict__ centers,
                                    float* __restrict__ c2g) {
  int b = blockIdx.x, k = threadIdx.x;
  if (k >= NK) return;
  int gy = k / 10, gx = k % 10;
  int cy = (int)((gy + 0.5) * 224.0 / 10.0);  // trunc like .astype(int32)
  int cx = (int)((gx + 0.5) * 224.0 / 10.0);
  int i = cy * IMGD + cx;
  const float ratio = ratio_f32();
  float c0 = x[((size_t)b * 3 + 0) * HW + i];
  float c1 = x[((size_t)b * 3 + 1) * HW + i];
  float c2 = x[((size_t)b * 3 + 2) * HW + i];
  float c3 = __fmul_rn((float)cy, ratio);
  float c4 = __fmul_rn((float)cx, ratio);
  float* c = centers + ((size_t)b * NK + k) * 5;
  c[0] = c0; c[1] = c1; c[2] = c2; c[3] = c3; c[4] = c4;
  // c2 = np.sum(centers*centers, axis=1): rounded products, sequential adds
  float s = __fmul_rn(c0, c0);
  s = __fadd_rn(s, __fmul_rn(c1, c1));
  s = __fadd_rn(s, __fmul_rn(c2, c2));
  s = __fadd_rn(s, __fmul_rn(c3, c3));
  s = __fadd_rn(s, __fmul_rn(c4, c4));
  c2g[(size_t)b * NK + k] = s;
}

// distance op sequence — the single source of truth for bit-exactness:
// dot = fmul(f0,c0); fma(f1,c1); fma(f2,c2); fma(f3,c3); fma(f4,c4)
// d   = fsub(fadd(fsq, c2k), fmul(2, dot))
static __device__ __forceinline__ float dist5(float f0, float f1, float f2,
                                              float f3, float f4, float fsq,
                                              float4 c4v, float2 c2v) {
  float dot = __fmul_rn(f0, c4v.x);
  dot = __fmaf_rn(f1, c4v.y, dot);
  dot = __fmaf_rn(f2, c4v.z, dot);
  dot = __fmaf_rn(f3, c4v.w, dot);
  dot = __fmaf_rn(f4, c2v.x, dot);
  return __fsub_rn(__fadd_rn(fsq, c2v.y), __fmul_rn(2.0f, dot));
}

// fsq = np.sum(feat*feat): rounded products, sequential adds, no FMA
static __device__ __forceinline__ float fsq5(float f0, float f1, float f2,
                                             float f3, float f4) {
  float s = __fmul_rn(f0, f0);
  s = __fadd_rn(s, __fmul_rn(f1, f1));
  s = __fadd_rn(s, __fmul_rn(f2, f2));
  s = __fadd_rn(s, __fmul_rn(f3, f3));
  s = __fadd_rn(s, __fmul_rn(f4, f4));
  return s;
}

// ---------- fused assign+partial for one OpenBLAS k-block chunk ----------
// Labels for the chunk's pixels are computed in-block (identical ops to the
// full assign); the per-(k,chunk) f32 add chain stays ascending-pixel-order.
__global__ void __launch_bounds__(128) fused_assign_partial_kernel(
    const float* __restrict__ x, const float* __restrict__ centers,
    const float* __restrict__ c2g, float* __restrict__ partials) {
  __shared__ float4 ck4[NK];
  __shared__ float2 ck2[NK];
  __shared__ float4 stage[384];          // {r,g,b,-} per chunk pixel
  __shared__ unsigned int mask[NK * 12]; // 12 groups of 32 pixels
  int c = blockIdx.x, b = blockIdx.y;
  int tid = threadIdx.x;
  int start = (c < 129) ? c * 384 : 49536 + (c - 129) * 320;
  int len   = (c < 129) ? 384 : 320;

  const float* cb = centers + (size_t)b * NK * 5;
  const float* c2b = c2g + (size_t)b * NK;
  for (int k = tid; k < NK; k += 128) {
    ck4[k] = make_float4(cb[k * 5 + 0], cb[k * 5 + 1], cb[k * 5 + 2], cb[k * 5 + 3]);
    ck2[k] = make_float2(cb[k * 5 + 4], c2b[k]);
  }
  for (int t = tid; t < NK * 12; t += 128) mask[t] = 0u;
  __syncthreads();

  const float* x0 = x + (size_t)b * 3 * HW;
  const float ratio = ratio_f32();

  // 3 pixels per thread: t, t+128, t+256 (hoisted k-loop shares center loads)
  float f0[3], f1[3], f2[3], f3[3], f4[3], fq[3];
  float best[3]; int bk[3]; bool valid[3];
  for (int r = 0; r < 3; ++r) {
    int t = tid + r * 128;
    valid[r] = (t < len);
    int i = start + (valid[r] ? t : 0);
    int y = i / IMGD, xw = i - y * IMGD;
    f0[r] = x0[i]; f1[r] = x0[HW + i]; f2[r] = x0[2 * HW + i];
    f3[r] = __fmul_rn((float)y, ratio);
    f4[r] = __fmul_rn((float)xw, ratio);
    fq[r] = fsq5(f0[r], f1[r], f2[r], f3[r], f4[r]);
    best[r] = 3.4e38f; bk[r] = 0;
  }
  for (int k = 0; k < NK; ++k) {
    float4 c4v = ck4[k];
    float2 c2v = ck2[k];
    for (int r = 0; r < 3; ++r) {
      float d = dist5(f0[r], f1[r], f2[r], f3[r], f4[r], fq[r], c4v, c2v);
      if (d < best[r]) { best[r] = d; bk[r] = k; }  // first-index wins
    }
  }
  for (int r = 0; r < 3; ++r) {
    int t = tid + r * 128;
    if (valid[r]) {
      stage[t] = make_float4(f0[r], f1[r], f2[r], 0.0f);
      atomicOr(&mask[bk[r] * 12 + (t >> 5)], 1u << (t & 31));
    }
  }
  __syncthreads();

  int k = tid;
  if (k < NK) {
    float s0 = 0.f, s1 = 0.f, s2 = 0.f, s3 = 0.f, s4 = 0.f, s5 = 0.f;
    for (int g = 0; g < 12; ++g) {
      unsigned int m = mask[k * 12 + g];
      while (m) {
        int j = __ffs(m) - 1;   // ascending pixel order within group
        m &= m - 1;
        int t = (g << 5) + j;
        float4 v = stage[t];
        int i = start + t;
        int y = i / IMGD;
        int xw = i - y * IMGD;
        s0 = __fadd_rn(s0, v.x);
        s1 = __fadd_rn(s1, v.y);
        s2 = __fadd_rn(s2, v.z);
        s3 = __fadd_rn(s3, __fmul_rn((float)y, ratio));
        s4 = __fadd_rn(s4, __fmul_rn((float)xw, ratio));
        s5 += 1.0f;  // counts: exact
      }
    }
    float* p = partials + (((size_t)b * NCHUNK + c) * NK + k) * 6;
    p[0] = s0; p[1] = s1; p[2] = s2; p[3] = s3; p[4] = s4; p[5] = s5;
  }
}

// ---------- combine k-blocks in order + centroid update + c2 (all f32) ----------
__global__ void combine_update_kernel(float* __restrict__ centers,
                                      const float* __restrict__ partials,
                                      float* __restrict__ c2g) {
  int b = blockIdx.x, k = threadIdx.x;
  if (k >= NK) return;
  float s[6];
  const float* p0 = partials + (((size_t)b * NCHUNK + 0) * NK + k) * 6;
  for (int j = 0; j < 6; ++j) s[j] = p0[j];  // C = 0 + chunk0 (exact)
  for (int c = 1; c < NCHUNK; ++c) {
    const float* p = partials + (((size_t)b * NCHUNK + c) * NK + k) * 6;
    for (int j = 0; j < 6; ++j) s[j] = __fadd_rn(s[j], p[j]);
  }
  float* cc = centers + ((size_t)b * NK + k) * 5;
  float cnt = s[5];
  if (cnt > 0.0f) {                 // where(cnt>0, new, centers)
    float m = fmaxf(cnt, 1.0f);     // np.maximum(cnt, 1.0): exact int in f32
    for (int j = 0; j < 5; ++j) cc[j] = __fdiv_rn(s[j], m);
  }
  // recompute c2 from the (possibly unchanged) stored center, same op order
  float c0 = cc[0], c1 = cc[1], c2 = cc[2], c3 = cc[3], c4 = cc[4];
  float t = __fmul_rn(c0, c0);
  t = __fadd_rn(t, __fmul_rn(c1, c1));
  t = __fadd_rn(t, __fmul_rn(c2, c2));
  t = __fadd_rn(t, __fmul_rn(c3, c3));
  t = __fadd_rn(t, __fmul_rn(c4, c4));
  c2g[(size_t)b * NK + k] = t;
}

// ---------- final full-image assignment: 4 px/thread, packed LDS centers ----------
__global__ void __launch_bounds__(256) assign_kernel(
    const float* __restrict__ x, const float* __restrict__ centers,
    const float* __restrict__ c2g, int* __restrict__ labels) {
  __shared__ float4 ck4[NK];
  __shared__ float2 ck2[NK];
  int b = blockIdx.y;
  int tid = threadIdx.x;
  int base = blockIdx.x * 1024;   // grid.x = 49 -> 49*1024 = 50176 exact

  const float* cb = centers + (size_t)b * NK * 5;
  const float* c2b = c2g + (size_t)b * NK;
  for (int k = tid; k < NK; k += 256) {
    ck4[k] = make_float4(cb[k * 5 + 0], cb[k * 5 + 1], cb[k * 5 + 2], cb[k * 5 + 3]);
    ck2[k] = make_float2(cb[k * 5 + 4], c2b[k]);
  }
  __syncthreads();

  const float* x0 = x + (size_t)b * 3 * HW;
  const float ratio = ratio_f32();
  float f0[4], f1[4], f2[4], f3[4], f4[4], fq[4];
  float best[4]; int bk[4];
  for (int r = 0; r < 4; ++r) {
    int i = base + r * 256 + tid;   // coalesced
    int y = i / IMGD, xw = i - y * IMGD;
    f0[r] = x0[i]; f1[r] = x0[HW + i]; f2[r] = x0[2 * HW + i];
    f3[r] = __fmul_rn((float)y, ratio);
    f4[r] = __fmul_rn((float)xw, ratio);
    fq[r] = fsq5(f0[r], f1[r], f2[r], f3[r], f4[r]);
    best[r] = 3.4e38f; bk[r] = 0;
  }
  for (int k = 0; k < NK; ++k) {
    float4 c4v = ck4[k];
    float2 c2v = ck2[k];
    for (int r = 0; r < 4; ++r) {
      float d = dist5(f0[r], f1[r], f2[r], f3[r], f4[r], fq[r], c4v, c2v);
      if (d < best[r]) { best[r] = d; bk[r] = k; }  // first-index wins
    }
  }
  int* lb = labels + (size_t)b * HW;
  for (int r = 0; r < 4; ++r) lb[base + r * 256 + tid] = bk[r];
}

// ---------- embed: block = (b,p,q); LDS bins per (k,c); direct stores ----------
__global__ void __launch_bounds__(256) embed_kernel(
    const float* __restrict__ x, const int* __restrict__ labels,
    const float* __restrict__ A, float* __restrict__ out) {
  __shared__ float sk[NK * 3];
  int b = blockIdx.y;
  int p = blockIdx.x >> 4;
  int q = blockIdx.x & 15;
  int tid = threadIdx.x;
  for (int t = tid; t < NK * 3; t += 256) sk[t] = 0.0f;
  __syncthreads();

  // A[p,h] support: h in [14p-7, 14p+20] clipped
  int h0 = max(0, 14 * p - 7), h1 = min(IMGD - 1, 14 * p + 20);
  int w0 = max(0, 14 * q - 7), w1 = min(IMGD - 1, 14 * q + 20);
  int hl = h1 - h0 + 1, wl = w1 - w0 + 1;
  int n = hl * wl;

  const float* xb = x + (size_t)b * 3 * HW;
  const int* lb = labels + (size_t)b * HW;
  const float* Ap = A + p * IMGD;
  const float* Aq = A + q * IMGD;

  for (int idx = tid; idx < n; idx += 256) {
    int dh = idx / wl;
    int hh = h0 + dh;
    int ww = w0 + (idx - dh * wl);
    int i = hh * IMGD + ww;
    float wgt = Ap[hh] * Aq[ww];
    int k = lb[i];
    atomicAdd(&sk[k * 3 + 0], wgt * xb[i]);
    atomicAdd(&sk[k * 3 + 1], wgt * xb[HW + i]);
    atomicAdd(&sk[k * 3 + 2], wgt * xb[2 * HW + i]);
  }
  __syncthreads();

  float* outb = out + (size_t)b * OUT_PER_B;
  int base = p * 48 + q * 3;
  for (int t = tid; t < NK * 3; t += 256) {
    int k = t / 3, c = t - 3 * k;
    int f = k * 768 + base + c;           // flat [K,P,P,C] index
    outb[(f & 255) * 300 + (f >> 8)] = sk[t];  // view(B,300,256) + transpose
  }
}

extern "C" void kernel_launch(void* const* d_in, const int* in_sizes, int n_in,
                              void* d_out, int out_size, void* d_ws, size_t ws_size,
                              hipStream_t stream) {
  const float* x = (const float*)d_in[0];
  float* out = (float*)d_out;
  char* ws = (char*)d_ws;
  // ws layout:
  float* A        = (float*)(ws);              // 14336 B
  float* centers  = (float*)(ws + 16384);      // 16000 B
  float* c2g      = (float*)(ws + 49152);      // 3200 B
  int*   labels   = (int*)(ws + 90112);        // 1605632 B
  float* partials = (float*)(ws + 1703936);    // 8*131*100*6*4 = 2515200 B

  build_A_kernel<<<16, 256, 0, stream>>>(A);
  init_centers_kernel<<<NB, 128, 0, stream>>>(x, centers, c2g);

  dim3 cgrid(NCHUNK, NB);         // 131 x 8
  for (int it = 0; it < 10; ++it) {
    fused_assign_partial_kernel<<<cgrid, 128, 0, stream>>>(x, centers, c2g, partials);
    combine_update_kernel<<<NB, 128, 0, stream>>>(centers, partials, c2g);
  }
  dim3 agrid(49, NB);             // 49*1024 = 50176 exact
  assign_kernel<<<agrid, 256, 0, stream>>>(x, centers, c2g, labels);

  dim3 egrid(256, NB);            // (p*16+q) x b
  embed_kernel<<<egrid, 256, 0, stream>>>(x, labels, A, out);
}

// Round 8
// 549.921 us; speedup vs baseline: 2.3666x; 1.3394x over previous
//
#include <hip/hip_runtime.h>
#include <math.h>

#define IMGD 224
#define HW 50176      // 224*224
#define NK 100
#define NB 8
#define OUT_PER_B 76800   // 100*16*16*3 = 300*256
#define NCHUNK 131        // OpenBLAS k-blocking of 50176: 129x384, 320, 320

// ratio = 10.0 / sqrt(224*224/100) in f64, rounded to f32 when numpy multiplies
// the f32 arange arrays by the weak python scalar.
static __device__ __forceinline__ float ratio_f32() {
  return (float)(10.0 / sqrt(224.0 * 224.0 / 100.0));
}

// ---------- resize matrix A[16][224], jax linear+antialias semantics ----------
__global__ void build_A_kernel(float* __restrict__ A) {
  __shared__ float red[256];
  int p = blockIdx.x;   // 0..15
  int h = threadIdx.x;  // 0..255
  float tri = 0.0f;
  if (h < IMGD) {
    float center = (p + 0.5f) * 14.0f - 0.5f;       // sample_f
    float xd = fabsf(center - (float)h) / 14.0f;    // / kernel_scale
    tri = fmaxf(0.0f, 1.0f - xd);
  }
  red[h] = tri;
  __syncthreads();
  for (int s = 128; s > 0; s >>= 1) {
    if (h < s) red[h] += red[h + s];
    __syncthreads();
  }
  float Z = red[0];
  if (h < IMGD) A[p * IMGD + h] = tri / Z;
}

// ---------- SLIC: grid-init centers (f32, mirroring numpy) + c2 ----------
__global__ void init_centers_kernel(const float* __restrict__ x,
                                    float* __restrict__ centers,
                                    float* __restrict__ c2g) {
  int b = blockIdx.x, k = threadIdx.x;
  if (k >= NK) return;
  int gy = k / 10, gx = k % 10;
  int cy = (int)((gy + 0.5) * 224.0 / 10.0);  // trunc like .astype(int32)
  int cx = (int)((gx + 0.5) * 224.0 / 10.0);
  int i = cy * IMGD + cx;
  const float ratio = ratio_f32();
  float c0 = x[((size_t)b * 3 + 0) * HW + i];
  float c1 = x[((size_t)b * 3 + 1) * HW + i];
  float c2 = x[((size_t)b * 3 + 2) * HW + i];
  float c3 = __fmul_rn((float)cy, ratio);
  float c4 = __fmul_rn((float)cx, ratio);
  float* c = centers + ((size_t)b * NK + k) * 5;
  c[0] = c0; c[1] = c1; c[2] = c2; c[3] = c3; c[4] = c4;
  // c2 = np.sum(centers*centers, axis=1): rounded products, sequential adds
  float s = __fmul_rn(c0, c0);
  s = __fadd_rn(s, __fmul_rn(c1, c1));
  s = __fadd_rn(s, __fmul_rn(c2, c2));
  s = __fadd_rn(s, __fmul_rn(c3, c3));
  s = __fadd_rn(s, __fmul_rn(c4, c4));
  c2g[(size_t)b * NK + k] = s;
}

// distance op sequence — the single source of truth for bit-exactness:
// dot = fmul(f0,c0); fma(f1,c1); fma(f2,c2); fma(f3,c3); fma(f4,c4)
// d   = fsub(fadd(fsq, c2k), fmul(2, dot))
static __device__ __forceinline__ float dist5(float f0, float f1, float f2,
                                              float f3, float f4, float fsq,
                                              float4 c4v, float2 c2v) {
  float dot = __fmul_rn(f0, c4v.x);
  dot = __fmaf_rn(f1, c4v.y, dot);
  dot = __fmaf_rn(f2, c4v.z, dot);
  dot = __fmaf_rn(f3, c4v.w, dot);
  dot = __fmaf_rn(f4, c2v.x, dot);
  return __fsub_rn(__fadd_rn(fsq, c2v.y), __fmul_rn(2.0f, dot));
}

// fsq = np.sum(feat*feat): rounded products, sequential adds, no FMA
static __device__ __forceinline__ float fsq5(float f0, float f1, float f2,
                                             float f3, float f4) {
  float s = __fmul_rn(f0, f0);
  s = __fadd_rn(s, __fmul_rn(f1, f1));
  s = __fadd_rn(s, __fmul_rn(f2, f2));
  s = __fadd_rn(s, __fmul_rn(f3, f3));
  s = __fadd_rn(s, __fmul_rn(f4, f4));
  return s;
}

// ---------- fused assign+partial for one OpenBLAS k-block chunk ----------
// Assign in-block (identical ops to full assign). Partial sums via stable
// counting-sort compaction: per-(k,chunk) add chain stays ascending-pixel
// order -> bit-identical; only the member *search* is parallelized.
__global__ void __launch_bounds__(256) fused_assign_partial_kernel(
    const float* __restrict__ x, const float* __restrict__ centers,
    const float* __restrict__ c2g, float* __restrict__ partials) {
  __shared__ float4 ck4[NK];
  __shared__ float2 ck2[NK];
  __shared__ float4 stage4[384];            // {r,g,b,f3}
  __shared__ float  stagef4[384];           // f4
  __shared__ unsigned int mask[NK * 12];    // 12 groups of 32 pixels
  __shared__ unsigned short ppk[NK * 12];   // per-(k,g) exclusive popcount prefix
  __shared__ unsigned short list16[384];    // compacted members, ascending t per k
  __shared__ int cnt[128];
  __shared__ int offx[128];
  int c = blockIdx.x, b = blockIdx.y;
  int tid = threadIdx.x;
  int start = (c < 129) ? c * 384 : 49536 + (c - 129) * 320;
  int len   = (c < 129) ? 384 : 320;

  const float* cb = centers + (size_t)b * NK * 5;
  const float* c2b = c2g + (size_t)b * NK;
  if (tid < NK) {
    ck4[tid] = make_float4(cb[tid * 5 + 0], cb[tid * 5 + 1], cb[tid * 5 + 2], cb[tid * 5 + 3]);
    ck2[tid] = make_float2(cb[tid * 5 + 4], c2b[tid]);
  }
  for (int t = tid; t < NK * 12; t += 256) mask[t] = 0u;
  __syncthreads();

  const float* x0 = x + (size_t)b * 3 * HW;
  const float ratio = ratio_f32();

  // pixel t0 = tid (always < len since len>=320... only for tid<len), t1 guarded
  bool v0 = tid < len;          // len=320: tids 320..383 don't exist (tid<256) -> always true
  int t1 = 256 + tid;
  bool v1 = t1 < len;

  int i0 = start + (v0 ? tid : 0);
  int y0 = i0 / IMGD, w0 = i0 - y0 * IMGD;
  float a0 = x0[i0], a1 = x0[HW + i0], a2 = x0[2 * HW + i0];
  float a3 = __fmul_rn((float)y0, ratio), a4 = __fmul_rn((float)w0, ratio);
  float aq = fsq5(a0, a1, a2, a3, a4);

  int i1 = start + (v1 ? t1 : 0);
  int y1 = i1 / IMGD, w1 = i1 - y1 * IMGD;
  float e0 = x0[i1], e1 = x0[HW + i1], e2 = x0[2 * HW + i1];
  float e3 = __fmul_rn((float)y1, ratio), e4 = __fmul_rn((float)w1, ratio);
  float eq = fsq5(e0, e1, e2, e3, e4);

  float bestA = 3.4e38f, bestE = 3.4e38f;
  int bkA = 0, bkE = 0;
  for (int k = 0; k < NK; ++k) {
    float4 c4v = ck4[k];
    float2 c2v = ck2[k];
    float dA = dist5(a0, a1, a2, a3, a4, aq, c4v, c2v);
    float dE = dist5(e0, e1, e2, e3, e4, eq, c4v, c2v);
    if (dA < bestA) { bestA = dA; bkA = k; }  // first-index wins (np.argmin)
    if (dE < bestE) { bestE = dE; bkE = k; }
  }
  if (v0) {
    stage4[tid] = make_float4(a0, a1, a2, a3);
    stagef4[tid] = a4;
    atomicOr(&mask[bkA * 12 + (tid >> 5)], 1u << (tid & 31));
  }
  if (v1) {
    stage4[t1] = make_float4(e0, e1, e2, e3);
    stagef4[t1] = e4;
    atomicOr(&mask[bkE * 12 + (t1 >> 5)], 1u << (t1 & 31));
  }
  __syncthreads();

  // per-k cumulative popcounts over the 12 groups
  if (tid < NK) {
    int s = 0;
    for (int g = 0; g < 12; ++g) {
      ppk[tid * 12 + g] = (unsigned short)s;
      s += __popc(mask[tid * 12 + g]);
    }
    cnt[tid] = s;
  } else if (tid < 128) {
    cnt[tid] = 0;
  }
  __syncthreads();

  // inclusive prefix-sum of cnt[0..127] into offx (Hillis-Steele)
  if (tid < 128) offx[tid] = cnt[tid];
  __syncthreads();
  for (int d = 1; d < 128; d <<= 1) {
    int val = 0;
    if (tid < 128 && tid >= d) val = offx[tid - d];
    __syncthreads();
    if (tid < 128 && tid >= d) offx[tid] += val;
    __syncthreads();
  }

  // stable scatter: list position = (off[k]-cnt[k]) + rank_within_k(t)
  if (v0) {
    int g = tid >> 5, j = tid & 31;
    int rank = ppk[bkA * 12 + g] + __popc(mask[bkA * 12 + g] & ((1u << j) - 1u));
    list16[offx[bkA] - cnt[bkA] + rank] = (unsigned short)tid;
  }
  if (v1) {
    int g = t1 >> 5, j = t1 & 31;
    int rank = ppk[bkE * 12 + g] + __popc(mask[bkE * 12 + g] & ((1u << j) - 1u));
    list16[offx[bkE] - cnt[bkE] + rank] = (unsigned short)t1;
  }
  __syncthreads();

  // scan: thread k walks its compacted list (ascending t), pipelined reads
  if (tid < NK) {
    int k = tid;
    int n = cnt[k];
    int base = offx[k] - n;
    float s0 = 0.f, s1 = 0.f, s2 = 0.f, s3 = 0.f, s4 = 0.f, s5 = 0.f;
    int t = (n > 0) ? (int)list16[base] : 0;
    for (int m = 0; m < n; ++m) {
      int tc = t;
      if (m + 1 < n) t = (int)list16[base + m + 1];  // prefetch next index
      float4 v = stage4[tc];
      float w = stagef4[tc];
      s0 = __fadd_rn(s0, v.x);
      s1 = __fadd_rn(s1, v.y);
      s2 = __fadd_rn(s2, v.z);
      s3 = __fadd_rn(s3, v.w);
      s4 = __fadd_rn(s4, w);
      s5 += 1.0f;  // counts: exact
    }
    float* p = partials + (((size_t)b * NCHUNK + c) * NK + k) * 6;
    p[0] = s0; p[1] = s1; p[2] = s2; p[3] = s3; p[4] = s4; p[5] = s5;
  }
}

// ---------- combine k-blocks in order + centroid update + c2 (all f32) ----------
__global__ void combine_update_kernel(float* __restrict__ centers,
                                      const float* __restrict__ partials,
                                      float* __restrict__ c2g) {
  int b = blockIdx.x, k = threadIdx.x;
  if (k >= NK) return;
  float s[6];
  const float* p0 = partials + (((size_t)b * NCHUNK + 0) * NK + k) * 6;
  for (int j = 0; j < 6; ++j) s[j] = p0[j];  // C = 0 + chunk0 (exact)
  for (int c = 1; c < NCHUNK; ++c) {
    const float* p = partials + (((size_t)b * NCHUNK + c) * NK + k) * 6;
    for (int j = 0; j < 6; ++j) s[j] = __fadd_rn(s[j], p[j]);
  }
  float* cc = centers + ((size_t)b * NK + k) * 5;
  float cnt = s[5];
  if (cnt > 0.0f) {                 // where(cnt>0, new, centers)
    float m = fmaxf(cnt, 1.0f);     // np.maximum(cnt, 1.0): exact int in f32
    for (int j = 0; j < 5; ++j) cc[j] = __fdiv_rn(s[j], m);
  }
  // recompute c2 from the (possibly unchanged) stored center, same op order
  float c0 = cc[0], c1 = cc[1], c2 = cc[2], c3 = cc[3], c4 = cc[4];
  float t = __fmul_rn(c0, c0);
  t = __fadd_rn(t, __fmul_rn(c1, c1));
  t = __fadd_rn(t, __fmul_rn(c2, c2));
  t = __fadd_rn(t, __fmul_rn(c3, c3));
  t = __fadd_rn(t, __fmul_rn(c4, c4));
  c2g[(size_t)b * NK + k] = t;
}

// ---------- final full-image assignment: 4 px/thread, packed LDS centers ----------
__global__ void __launch_bounds__(256) assign_kernel(
    const float* __restrict__ x, const float* __restrict__ centers,
    const float* __restrict__ c2g, int* __restrict__ labels) {
  __shared__ float4 ck4[NK];
  __shared__ float2 ck2[NK];
  int b = blockIdx.y;
  int tid = threadIdx.x;
  int base = blockIdx.x * 1024;   // grid.x = 49 -> 49*1024 = 50176 exact

  const float* cb = centers + (size_t)b * NK * 5;
  const float* c2b = c2g + (size_t)b * NK;
  for (int k = tid; k < NK; k += 256) {
    ck4[k] = make_float4(cb[k * 5 + 0], cb[k * 5 + 1], cb[k * 5 + 2], cb[k * 5 + 3]);
    ck2[k] = make_float2(cb[k * 5 + 4], c2b[k]);
  }
  __syncthreads();

  const float* x0 = x + (size_t)b * 3 * HW;
  const float ratio = ratio_f32();
  float f0[4], f1[4], f2[4], f3[4], f4[4], fq[4];
  float best[4]; int bk[4];
  for (int r = 0; r < 4; ++r) {
    int i = base + r * 256 + tid;   // coalesced
    int y = i / IMGD, xw = i - y * IMGD;
    f0[r] = x0[i]; f1[r] = x0[HW + i]; f2[r] = x0[2 * HW + i];
    f3[r] = __fmul_rn((float)y, ratio);
    f4[r] = __fmul_rn((float)xw, ratio);
    fq[r] = fsq5(f0[r], f1[r], f2[r], f3[r], f4[r]);
    best[r] = 3.4e38f; bk[r] = 0;
  }
  for (int k = 0; k < NK; ++k) {
    float4 c4v = ck4[k];
    float2 c2v = ck2[k];
    for (int r = 0; r < 4; ++r) {
      float d = dist5(f0[r], f1[r], f2[r], f3[r], f4[r], fq[r], c4v, c2v);
      if (d < best[r]) { best[r] = d; bk[r] = k; }  // first-index wins
    }
  }
  int* lb = labels + (size_t)b * HW;
  for (int r = 0; r < 4; ++r) lb[base + r * 256 + tid] = bk[r];
}

// ---------- embed: block = (b,p,q); LDS bins per (k,c); direct stores ----------
__global__ void __launch_bounds__(256) embed_kernel(
    const float* __restrict__ x, const int* __restrict__ labels,
    const float* __restrict__ A, float* __restrict__ out) {
  __shared__ float sk[NK * 3];
  int b = blockIdx.y;
  int p = blockIdx.x >> 4;
  int q = blockIdx.x & 15;
  int tid = threadIdx.x;
  for (int t = tid; t < NK * 3; t += 256) sk[t] = 0.0f;
  __syncthreads();

  // A[p,h] support: h in [14p-7, 14p+20] clipped
  int h0 = max(0, 14 * p - 7), h1 = min(IMGD - 1, 14 * p + 20);
  int w0 = max(0, 14 * q - 7), w1 = min(IMGD - 1, 14 * q + 20);
  int hl = h1 - h0 + 1, wl = w1 - w0 + 1;
  int n = hl * wl;

  const float* xb = x + (size_t)b * 3 * HW;
  const int* lb = labels + (size_t)b * HW;
  const float* Ap = A + p * IMGD;
  const float* Aq = A + q * IMGD;

  for (int idx = tid; idx < n; idx += 256) {
    int dh = idx / wl;
    int hh = h0 + dh;
    int ww = w0 + (idx - dh * wl);
    int i = hh * IMGD + ww;
    float wgt = Ap[hh] * Aq[ww];
    int k = lb[i];
    atomicAdd(&sk[k * 3 + 0], wgt * xb[i]);
    atomicAdd(&sk[k * 3 + 1], wgt * xb[HW + i]);
    atomicAdd(&sk[k * 3 + 2], wgt * xb[2 * HW + i]);
  }
  __syncthreads();

  float* outb = out + (size_t)b * OUT_PER_B;
  int base = p * 48 + q * 3;
  for (int t = tid; t < NK * 3; t += 256) {
    int k = t / 3, c = t - 3 * k;
    int f = k * 768 + base + c;           // flat [K,P,P,C] index
    outb[(f & 255) * 300 + (f >> 8)] = sk[t];  // view(B,300,256) + transpose
  }
}

extern "C" void kernel_launch(void* const* d_in, const int* in_sizes, int n_in,
                              void* d_out, int out_size, void* d_ws, size_t ws_size,
                              hipStream_t stream) {
  const float* x = (const float*)d_in[0];
  float* out = (float*)d_out;
  char* ws = (char*)d_ws;
  // ws layout:
  float* A        = (float*)(ws);              // 14336 B
  float* centers  = (float*)(ws + 16384);      // 16000 B
  float* c2g      = (float*)(ws + 49152);      // 3200 B
  int*   labels   = (int*)(ws + 90112);        // 1605632 B
  float* partials = (float*)(ws + 1703936);    // 8*131*100*6*4 = 2515200 B

  build_A_kernel<<<16, 256, 0, stream>>>(A);
  init_centers_kernel<<<NB, 128, 0, stream>>>(x, centers, c2g);

  dim3 cgrid(NCHUNK, NB);         // 131 x 8
  for (int it = 0; it < 10; ++it) {
    fused_assign_partial_kernel<<<cgrid, 256, 0, stream>>>(x, centers, c2g, partials);
    combine_update_kernel<<<NB, 128, 0, stream>>>(centers, partials, c2g);
  }
  dim3 agrid(49, NB);             // 49*1024 = 50176 exact
  assign_kernel<<<agrid, 256, 0, stream>>>(x, centers, c2g, labels);

  dim3 egrid(256, NB);            // (p*16+q) x b
  embed_kernel<<<egrid, 256, 0, stream>>>(x, labels, A, out);
}